// Round 8
// baseline (342.391 us; speedup 1.0000x reference)
//
#include <hip/hip_runtime.h>

#define D_DIM 256
#define N_TOK 32768
#define K_CB  8192
#define TAU   0.12f
#define ZC_CAP 4096
#define SLABS 32            // rescan: 32 slabs x 256 codes per 64-token group
#define SLABW 256

typedef float    f32x16 __attribute__((ext_vector_type(16)));
typedef float    f32x4  __attribute__((ext_vector_type(4)));
typedef _Float16 f16x8  __attribute__((ext_vector_type(8)));

// ---- workspace layout (bytes) ----
#define OFF_ESQ   0                        // 8192 f32 (32 KB)
#define OFF_CNT   32768                    // int
#define OFF_GDONE 33024                    // 512 i32 (2 KB)
#define OFF_LIST  35072                    // 32768 i32 (128 KB)
#define OFF_FIXB  166144                   // 32768 u64 (256 KB)
#define OFF_EHT   524288                   // 32*8192*8 f16 = 4 MB
#define OFF_ZC    (OFF_EHT + 4194304)      // 4096 tokens x 256 f32 = 4 MB
#define MAXGRP    512
#define WS_NEED   ((size_t)(OFF_ZC + 4194304))

#define SMEM_MAIN 65536

// ===========================================================================
// P: eht[c][k][8] = f16 of e[k][8c+j], coalesced stores (lanes k-major ->
// 16B/lane consecutive). esq[k] via LDS reduce. Zeros cnt + gdone.
// ===========================================================================
__global__ __launch_bounds__(256) void eprep_kernel(const float* __restrict__ e,
                                                    short* __restrict__ eht,
                                                    float* __restrict__ esq,
                                                    int* __restrict__ cnt,
                                                    int* __restrict__ gdone) {
  __shared__ float ps[4 * 64];
  const int tid = threadIdx.x;
  const int kk = tid & 63, cc = tid >> 6;     // code-in-group, c-quarter
  const int k = blockIdx.x * 64 + kk;
  if (blockIdx.x == 0) {
    if (tid == 0) *cnt = 0;
    if (tid < 256) { gdone[tid] = 0; gdone[tid + 256] = 0; }
  }
  _Float16* ef = (_Float16*)eht;
  float ss = 0.f;
  #pragma unroll
  for (int c2 = 0; c2 < 8; ++c2) {
    const int c = cc * 8 + c2;
    f32x4 v0 = *(const f32x4*)(e + (size_t)k * D_DIM + c * 8);
    f32x4 v1 = *(const f32x4*)(e + (size_t)k * D_DIM + c * 8 + 4);
    float v[8] = {v0[0], v0[1], v0[2], v0[3], v1[0], v1[1], v1[2], v1[3]};
    f16x8 hv;
    #pragma unroll
    for (int i = 0; i < 8; ++i) {
      ss += v[i] * v[i];
      hv[i] = (_Float16)v[i];               // RNE
    }
    *(f16x8*)(ef + ((size_t)c * K_CB + k) * 8) = hv;   // coalesced over kk
  }
  ps[cc * 64 + kk] = ss;
  __syncthreads();
  if (tid < 64)
    esq[blockIdx.x * 64 + tid] = ps[tid] + ps[64 + tid] + ps[128 + tid] + ps[192 + tid];
}

// ===========================================================================
// Main R8: halve LDS reads per MFMA. R7 pipe ledger (per CU): LDS 82us
// (1 ds_read_b128 z-frag per MFMA, #1 pipe), MFMA 55, L2 ~30, VALU ~35;
// wall 193 = 2.3x max pipe at 4 waves/SIMD (LDS-pinned occupancy).
// Change: f=2, j=2 wave shape -- wave (th=w>>3, cg=w&7) owns 64 codes x
// 64 tokens; per dc: 2 a-loads + 2 b-reads -> 4 MFMAs = 0.5 LDS reads per
// MFMA (floor 41us). th-split doubles issued e to 2 GB (~10 TB/s agg,
// under the ~12 TB/s fabric plateau R3 demonstrated at HALF this TLP).
// Registers (R6 calibration: VGPR_Count=arch only; arch+AGPR<=128 @4w/SIMD;
// R6=52+64=116): acc[2][2]=64 AGPR + ~60 arch = ~124. Spill check =
// WRITE_SIZE stays ~33 MB. Everything else (fused merge/tail) unchanged.
// ===========================================================================
__global__ __launch_bounds__(1024, 4) void vq_main_kernel(
    const float* __restrict__ z, const float* __restrict__ e,
    const float* __restrict__ esq_g,
    const short* __restrict__ eht,
    float* __restrict__ out,
    int* __restrict__ cnt, int* __restrict__ list,
    unsigned long long* __restrict__ fixb, float* __restrict__ zc) {
  extern __shared__ char smem[];
  _Float16* zs = (_Float16*)smem;               // [32 c][128 t][8] f16 = 64 KB
  __shared__ int fin[128], slo[128];

  const int tid  = threadIdx.x;
  const int w    = tid >> 6;          // wave 0..15
  const int lane = tid & 63;
  const int half = lane >> 5;
  const int l31  = lane & 31;
  const int th   = w >> 3;            // token half (0/1): 64 tokens
  const int cg   = w & 7;             // code subgroup: 64 codes (f=2)
  const int n0   = blockIdx.x * 128;  // 256 blocks x 128 tokens
  const _Float16* ef = (const _Float16*)eht;

  // ---- convert -2*z to fp16 directly into LDS (fused zprep) ----
  {
    const int t  = tid & 127;
    const int cb = (tid >> 7) * 4;    // 8 thread-groups x 4 c's
    #pragma unroll
    for (int cc = 0; cc < 4; ++cc) {
      const int c = cb + cc;
      f16x8 hv;
      #pragma unroll
      for (int i = 0; i < 8; ++i)
        hv[i] = (_Float16)(-2.0f * z[(size_t)(c * 8 + i) * N_TOK + n0 + t]); // coalesced over t
      *(f16x8*)(zs + ((size_t)c * 128 + t) * 8) = hv;
    }
  }
  __syncthreads();   // the only barrier before the merge

  float bestv[2] = {3.4e38f, 3.4e38f};
  float secv[2]  = {3.4e38f, 3.4e38f};
  int   bestk[2] = {0, 0};

  for (int k0 = 0; k0 < K_CB; k0 += 512) {
    const int kb = k0 + cg * 64;

    // ---- acc init = esq broadcast from GLOBAL (L2-hit; no LDS stage) ----
    f32x16 acc[2][2];
    #pragma unroll
    for (int f = 0; f < 2; ++f) {
      const int qb = kb + 32 * f + 4 * half;
      #pragma unroll
      for (int g = 0; g < 4; ++g) {
        f32x4 q = *(const f32x4*)(esq_g + qb + 8 * g);
        #pragma unroll
        for (int r = 0; r < 4; ++r) {
          const float qv = q[r];
          acc[f][0][g * 4 + r] = qv;
          acc[f][1][g * 4 + r] = qv;
        }
      }
    }

    #pragma unroll 2
    for (int dc = 0; dc < 16; ++dc) {
      f16x8 a[2], b[2];
      const size_t ebase = ((size_t)(2 * dc + half) * K_CB + kb + l31) * 8;
      a[0] = *(const f16x8*)(ef + ebase);            // global, coalesced 16B/lane
      a[1] = *(const f16x8*)(ef + ebase + 32 * 8);
      const int zb = ((2 * dc + half) * 128 + th * 64 + l31) * 8;
      b[0] = *(const f16x8*)(zs + zb);
      b[1] = *(const f16x8*)(zs + zb + 32 * 8);
      #pragma unroll
      for (int f = 0; f < 2; ++f)
        #pragma unroll
        for (int j = 0; j < 2; ++j)
          acc[f][j] = __builtin_amdgcn_mfma_f32_32x32x16_f16(a[f], b[j], acc[f][j], 0, 0, 0);
    }

    // epilogue: running best/second per token-group j (k ascending per lane)
    #pragma unroll
    for (int f = 0; f < 2; ++f) {
      const int base = kb + 32 * f + 4 * half;
      #pragma unroll
      for (int g = 0; g < 4; ++g) {
        #pragma unroll
        for (int r = 0; r < 4; ++r) {
          const int reg = g * 4 + r;
          const int kglob = base + 8 * g + r;
          #pragma unroll
          for (int j = 0; j < 2; ++j) {
            const float s = acc[f][j][reg];
            if (s < bestv[j]) { secv[j] = bestv[j]; bestv[j] = s; bestk[j] = kglob; }
            else if (s < secv[j]) secv[j] = s;
          }
        }
      }
    }
  }

  // ---- cross-wave merge: 16 partials per token (8 cg x 2 half-lanes) ----
  __syncthreads();
  float* pv  = (float*)(smem);                  // [16][128] = 8 KB
  int*   pk  = (int*)  (smem + 8192);
  float* ps2 = (float*)(smem + 16384);
  const int slot = cg * 2 + half;
  #pragma unroll
  for (int j = 0; j < 2; ++j) {
    const int t = th * 64 + j * 32 + l31;
    pv [slot * 128 + t] = bestv[j];
    pk [slot * 128 + t] = bestk[j];
    ps2[slot * 128 + t] = secv[j];
  }
  __syncthreads();
  if (tid < 128) {
    const int t = tid;
    float bv = pv[t]; int bk = pk[t]; float sc = ps2[t];
    #pragma unroll
    for (int s2 = 1; s2 < 16; ++s2) {
      float v = pv[s2 * 128 + t]; int k2 = pk[s2 * 128 + t]; float s3 = ps2[s2 * 128 + t];
      if (v < bv || (v == bv && k2 < bk)) { sc = fminf(bv, s3); bv = v; bk = k2; }
      else                                { sc = fminf(sc, v); }
    }
    fin[t] = bk;
    int sl = -1;
    const int n = n0 + t;
    out[(size_t)D_DIM * N_TOK + n] = (float)bk;     // indices as float (exact)
    if (sc - bv < TAU) {                            // flag for exact rescan
      int p = atomicAdd(cnt, 1);
      list[p] = n;
      fixb[n] = 0xFFFFFFFFFFFFFFFFULL;
      if (p < ZC_CAP) sl = p;
    }
    slo[t] = sl;
  }
  __syncthreads();

  // ---- compact flagged z columns into zc (coalesced source for rescan) ----
  for (int tt = 0; tt < 128; ++tt) {
    const int p = slo[tt];                          // uniform broadcast
    if (p >= 0 && tid < 256)
      zc[(size_t)p * 256 + tid] = z[(size_t)tid * N_TOK + n0 + tt];
  }

  // ---- z_q gather: float4 codebook loads, coalesced stores over t ----
  {
    const int t = tid & 127, d0 = tid >> 7;         // d0 0..7
    const int kk = fin[t];
    const f32x4* row = (const f32x4*)(e + (size_t)kk * D_DIM) + d0 * 8;
    #pragma unroll 4
    for (int q = 0; q < 8; ++q) {
      f32x4 v = row[q];
      const int d = d0 * 32 + q * 4;
      out[(size_t)(d + 0) * N_TOK + n0 + t] = v[0];
      out[(size_t)(d + 1) * N_TOK + n0 + t] = v[1];
      out[(size_t)(d + 2) * N_TOK + n0 + t] = v[2];
      out[(size_t)(d + 3) * N_TOK + n0 + t] = v[3];
    }
  }
}

// ===========================================================================
// C2: exact fp32 rescan + finisher. Items = (64-token group) x (256-code
// slab); SLABS=32 items per group. Stage is bank-conflict-free (thread t
// owns token t -> consecutive LDS addresses). zc path coalesced f32x4;
// groups >= ZC_CAP/64 fall back to scattered z reads. atomicMin-merges
// packed (f32bits<<32|k); last-finishing item of a group writes idx + z_q.
// ===========================================================================
__global__ __launch_bounds__(256) void rescan_kernel(
    const float* __restrict__ z, const float* __restrict__ zc,
    const float* __restrict__ e,
    const float* __restrict__ esq, const int* __restrict__ cnt,
    const int* __restrict__ list, unsigned long long* __restrict__ fixb,
    int* __restrict__ gdone, float* __restrict__ out) {
  __shared__ float zs[D_DIM * 64];                 // 64 KB, zs[d*64 + t]
  __shared__ unsigned long long red[16 * 64];      // 8 KB
  __shared__ int fk[64], fn[64], lastflag;
  const int tid = threadIdx.x;
  const int c = *(volatile const int*)cnt;
  if (c == 0) return;
  int groups = (c + 63) >> 6;
  if (groups > MAXGRP) groups = MAXGRP;
  const int items = groups * SLABS;
  const int tx = tid & 15, ty = tid >> 4;

  for (int it = blockIdx.x; it < items; it += gridDim.x) {
    const int g = it / SLABS;
    const int slab = (it % SLABS) * SLABW;
    __syncthreads();                               // protect zs/red reuse
    // ---- stage z columns for this group ----
    if (g < (ZC_CAP >> 6)) {
      // compact path: thread t owns token t -> conflict-free LDS writes
      const int t = tid & 63, seg = tid >> 6;      // seg 0..3 (64 d's each)
      const int idx = g * 64 + t;
      const float* src = zc + (size_t)(idx < c ? idx : c - 1) * 256 + seg * 64;
      #pragma unroll
      for (int r = 0; r < 16; ++r) {
        f32x4 v = *(const f32x4*)(src + r * 4);
        const int d = seg * 64 + r * 4;
        zs[(d + 0) * 64 + t] = v[0];
        zs[(d + 1) * 64 + t] = v[1];
        zs[(d + 2) * 64 + t] = v[2];
        zs[(d + 3) * 64 + t] = v[3];
      }
    } else {
      // overflow fallback: scattered reads from z
      const int t = tid & 63, dq = tid >> 6;       // dq 0..3
      const int idx = g * 64 + t;
      const int n = list[idx < c ? idx : c - 1];
      #pragma unroll 4
      for (int dd = 0; dd < 64; ++dd) {
        const int d = dq * 64 + dd;
        zs[d * 64 + t] = z[(size_t)d * N_TOK + n];
      }
    }
    __syncthreads();

    unsigned long long lmin[4] = {~0ULL, ~0ULL, ~0ULL, ~0ULL};
    #pragma unroll
    for (int k0 = 0; k0 < SLABW; k0 += 64) {
      const f32x4* er[4]; float eqv[4];
      #pragma unroll
      for (int j = 0; j < 4; ++j) {
        int k = slab + k0 + ty + 16 * j;
        er[j] = (const f32x4*)(e + (size_t)k * D_DIM);
        eqv[j] = esq[k];
      }
      float acc[4][4];
      #pragma unroll
      for (int i = 0; i < 4; ++i)
        #pragma unroll
        for (int j = 0; j < 4; ++j) acc[i][j] = 0.f;
      #pragma unroll 4
      for (int d4 = 0; d4 < D_DIM / 4; ++d4) {
        f32x4 ev[4];
        #pragma unroll
        for (int j = 0; j < 4; ++j) ev[j] = er[j][d4];
        #pragma unroll
        for (int dd = 0; dd < 4; ++dd) {
          float zv[4];
          #pragma unroll
          for (int i = 0; i < 4; ++i) zv[i] = zs[(d4 * 4 + dd) * 64 + tx + 16 * i];
          #pragma unroll
          for (int i = 0; i < 4; ++i)
            #pragma unroll
            for (int j = 0; j < 4; ++j) acc[i][j] += zv[i] * ev[j][dd];
        }
      }
      #pragma unroll
      for (int j = 0; j < 4; ++j) {
        const int k = slab + k0 + ty + 16 * j;
        #pragma unroll
        for (int i = 0; i < 4; ++i) {
          float s = eqv[j] - 2.0f * acc[i][j] + 1024.0f;   // bias > 0 for packing
          unsigned long long p =
              ((unsigned long long)__float_as_uint(s) << 32) | (unsigned)k;
          lmin[i] = (p < lmin[i]) ? p : lmin[i];
        }
      }
    }
    #pragma unroll
    for (int i = 0; i < 4; ++i) red[ty * 64 + tx + 16 * i] = lmin[i];
    __syncthreads();
    if (tid < 64) {
      unsigned long long m = red[tid];
      #pragma unroll
      for (int t = 1; t < 16; ++t) {
        unsigned long long v = red[t * 64 + tid];
        m = (v < m) ? v : m;
      }
      const int idx = g * 64 + tid;
      const int n = list[idx < c ? idx : c - 1];
      atomicMin(&fixb[n], m);
    }
    // ---- completion: last item of this group writes outputs ----
    __threadfence();
    __syncthreads();
    if (tid == 0) lastflag = (atomicAdd(&gdone[g], 1) == SLABS - 1) ? 1 : 0;
    __syncthreads();
    if (lastflag) {
      if (tid < 64) {
        const int idx = g * 64 + tid;
        int kres = -1, n = -1;
        if (idx < c) {
          n = list[idx];
          unsigned long long mv = atomicMin(&fixb[n], 0xFFFFFFFFFFFFFFFFULL);
          kres = (int)(unsigned)(mv & 0xFFFFFFFFu);
          out[(size_t)D_DIM * N_TOK + n] = (float)kres;
        }
        fk[tid] = kres; fn[tid] = n;
      }
      __syncthreads();
      {
        const int t = tid & 63, dq = tid >> 6;
        const int kres = fk[t];
        if (kres >= 0) {
          const int n = fn[t];
          const float* row = e + (size_t)kres * D_DIM;
          #pragma unroll 4
          for (int dd = 0; dd < 64; ++dd) {
            const int d = dq * 64 + dd;
            out[(size_t)d * N_TOK + n] = row[d];
          }
        }
      }
    }
  }
}

// ======================= fallback (round-1 fp32 path) =======================
__global__ __launch_bounds__(256) void esq_kernel(const float* __restrict__ e,
                                                  float* __restrict__ esq) {
  const int wave = threadIdx.x >> 6, lane = threadIdx.x & 63;
  const int k = blockIdx.x * 4 + wave;
  const float4* row = (const float4*)(e + (size_t)k * D_DIM);
  float4 v = row[lane];
  float s = v.x*v.x + v.y*v.y + v.z*v.z + v.w*v.w;
  #pragma unroll
  for (int off = 32; off > 0; off >>= 1) s += __shfl_down(s, off, 64);
  if (lane == 0) esq[k] = s;
}

__global__ __launch_bounds__(256) void vq_kernel(const float* __restrict__ z,
                                                 const float* __restrict__ e,
                                                 const float* __restrict__ esq,
                                                 float* __restrict__ out) {
  __shared__ float zs[D_DIM][64];
  const int tid = threadIdx.x, tx = tid & 15, ty = tid >> 4;
  const int n0 = blockIdx.x * 64;
  {
    const int c = tid & 63, d0 = tid >> 6;
    #pragma unroll 4
    for (int d = d0; d < D_DIM; d += 4) zs[d][c] = z[(size_t)d * N_TOK + n0 + c];
  }
  __syncthreads();
  float bestv[4] = {3.4e38f,3.4e38f,3.4e38f,3.4e38f};
  int   besti[4] = {0,0,0,0};
  for (int k0 = 0; k0 < K_CB; k0 += 64) {
    const float4* er[4]; float eqv[4];
    #pragma unroll
    for (int j = 0; j < 4; ++j) {
      int k = k0 + ty + 16 * j;
      er[j] = (const float4*)(e + (size_t)k * D_DIM);
      eqv[j] = esq[k];
    }
    float acc[4][4];
    #pragma unroll
    for (int i = 0; i < 4; ++i)
      #pragma unroll
      for (int j = 0; j < 4; ++j) acc[i][j] = 0.f;
    #pragma unroll 4
    for (int d4 = 0; d4 < D_DIM/4; ++d4) {
      float4 ev[4];
      #pragma unroll
      for (int j = 0; j < 4; ++j) ev[j] = er[j][d4];
      #pragma unroll
      for (int dd = 0; dd < 4; ++dd) {
        float zv[4];
        #pragma unroll
        for (int i = 0; i < 4; ++i) zv[i] = zs[d4*4+dd][tx + 16*i];
        #pragma unroll
        for (int i = 0; i < 4; ++i)
          #pragma unroll
          for (int j = 0; j < 4; ++j) acc[i][j] += zv[i] * ((const float*)&ev[j])[dd];
      }
    }
    #pragma unroll
    for (int j = 0; j < 4; ++j) {
      int k = k0 + ty + 16 * j;
      #pragma unroll
      for (int i = 0; i < 4; ++i) {
        float s = eqv[j] - 2.0f * acc[i][j];
        if (s < bestv[i]) { bestv[i] = s; besti[i] = k; }
      }
    }
  }
  __syncthreads();
  float* lds = &zs[0][0];
  float* vred = lds; int* ired = (int*)lds + 1024; int* fin = (int*)lds + 2048;
  #pragma unroll
  for (int i = 0; i < 4; ++i) {
    int l = tx + 16 * i;
    vred[ty * 64 + l] = bestv[i]; ired[ty * 64 + l] = besti[i];
  }
  __syncthreads();
  if (tid < 64) {
    float bv = vred[tid]; int bi = ired[tid];
    #pragma unroll
    for (int t = 1; t < 16; ++t) {
      float v = vred[t*64+tid]; int ix = ired[t*64+tid];
      if (v < bv || (v == bv && ix < bi)) { bv = v; bi = ix; }
    }
    fin[tid] = bi;
    out[(size_t)D_DIM * N_TOK + n0 + tid] = (float)bi;
  }
  __syncthreads();
  {
    const int l = tid & 63, d0 = tid >> 6;
    const int kk = fin[l];
    const float* row = e + (size_t)kk * D_DIM;
    #pragma unroll 4
    for (int d = d0; d < D_DIM; d += 4) out[(size_t)d * N_TOK + n0 + l] = row[d];
  }
}

extern "C" void kernel_launch(void* const* d_in, const int* in_sizes, int n_in,
                              void* d_out, int out_size, void* d_ws, size_t ws_size,
                              hipStream_t stream) {
  const float* z = (const float*)d_in[0];
  const float* e = (const float*)d_in[1];
  float* out = (float*)d_out;
  char* ws = (char*)d_ws;

  if (ws_size >= WS_NEED) {
    float* esq = (float*)(ws + OFF_ESQ);
    int* cnt = (int*)(ws + OFF_CNT);
    int* gdone = (int*)(ws + OFF_GDONE);
    int* list = (int*)(ws + OFF_LIST);
    unsigned long long* fixb = (unsigned long long*)(ws + OFF_FIXB);
    short* eht = (short*)(ws + OFF_EHT);
    float* zc = (float*)(ws + OFF_ZC);

    (void)hipFuncSetAttribute((const void*)vq_main_kernel,
                              hipFuncAttributeMaxDynamicSharedMemorySize, SMEM_MAIN);

    eprep_kernel<<<128, 256, 0, stream>>>(e, eht, esq, cnt, gdone);
    vq_main_kernel<<<256, 1024, SMEM_MAIN, stream>>>(z, e, esq, eht,
                                                     out, cnt, list, fixb, zc);
    rescan_kernel<<<512, 256, 0, stream>>>(z, zc, e, esq, cnt, list, fixb, gdone, out);
  } else {
    float* esq = (float*)(ws);
    esq_kernel<<<K_CB / 4, 256, 0, stream>>>(e, esq);
    vq_kernel<<<N_TOK / 64, 256, 0, stream>>>(z, e, esq, out);
  }
}

// Round 10
// 334.263 us; speedup vs baseline: 1.0243x; 1.0243x over previous
//
#include <hip/hip_runtime.h>

#define D_DIM 256
#define N_TOK 32768
#define K_CB  8192
#define TAU   0.12f
#define ZC_CAP 4096
#define SLABS 32            // rescan: 32 slabs x 256 codes per 64-token group
#define SLABW 256

typedef float    f32x16 __attribute__((ext_vector_type(16)));
typedef float    f32x4  __attribute__((ext_vector_type(4)));
typedef _Float16 f16x8  __attribute__((ext_vector_type(8)));

// ---- workspace layout (bytes) ----
#define OFF_ESQ   0                        // 8192 f32 (32 KB)
#define OFF_CNT   32768                    // int
#define OFF_GDONE 33024                    // 512 i32 (2 KB)
#define OFF_LIST  35072                    // 32768 i32 (128 KB)
#define OFF_FIXB  166144                   // 32768 u64 (256 KB)
#define OFF_EHT   524288                   // 32*8192*8 f16 = 4 MB
#define OFF_ZC    (OFF_EHT + 4194304)      // 4096 tokens x 256 f32 = 4 MB
#define MAXGRP    512
#define WS_NEED   ((size_t)(OFF_ZC + 4194304))

// LDS: zs [0,64K) | es0 [64K,96K) | es1 [96K,128K) | eqs [128K,160K)
#define SMEM_MAIN 163840

#define GLOAD_LDS16(g, s) \
  __builtin_amdgcn_global_load_lds((const __attribute__((address_space(1))) unsigned int*)(g), \
                                   (__attribute__((address_space(3))) unsigned int*)(s), 16, 0, 0)

// ===========================================================================
// P: eht[c][k][8] = f16 of e[k][8c+j], coalesced stores (lanes k-major ->
// 16B/lane consecutive). esq[k] via LDS reduce. Zeros cnt + gdone.
// ===========================================================================
__global__ __launch_bounds__(256) void eprep_kernel(const float* __restrict__ e,
                                                    short* __restrict__ eht,
                                                    float* __restrict__ esq,
                                                    int* __restrict__ cnt,
                                                    int* __restrict__ gdone) {
  __shared__ float ps[4 * 64];
  const int tid = threadIdx.x;
  const int kk = tid & 63, cc = tid >> 6;     // code-in-group, c-quarter
  const int k = blockIdx.x * 64 + kk;
  if (blockIdx.x == 0) {
    if (tid == 0) *cnt = 0;
    if (tid < 256) { gdone[tid] = 0; gdone[tid + 256] = 0; }
  }
  _Float16* ef = (_Float16*)eht;
  float ss = 0.f;
  #pragma unroll
  for (int c2 = 0; c2 < 8; ++c2) {
    const int c = cc * 8 + c2;
    f32x4 v0 = *(const f32x4*)(e + (size_t)k * D_DIM + c * 8);
    f32x4 v1 = *(const f32x4*)(e + (size_t)k * D_DIM + c * 8 + 4);
    float v[8] = {v0[0], v0[1], v0[2], v0[3], v1[0], v1[1], v1[2], v1[3]};
    f16x8 hv;
    #pragma unroll
    for (int i = 0; i < 8; ++i) {
      ss += v[i] * v[i];
      hv[i] = (_Float16)v[i];               // RNE
    }
    *(f16x8*)(ef + ((size_t)c * K_CB + k) * 8) = hv;   // coalesced over kk
  }
  ps[cc * 64 + kk] = ss;
  __syncthreads();
  if (tid < 64)
    esq[blockIdx.x * 64 + tid] = ps[tid] + ps[64 + tid] + ps[128 + tid] + ps[192 + tid];
}

// stage one 32-dim x 512-code e-sub-tile (32 KB) into LDS via global_load_lds.
// LDS dest: wave-uniform base + lane*16 (HW constraint m104). Global src is
// per-lane: unit u = q*1024 + w*64 + lane; chunk = u>>9 (c-group), off = u&511.
static __device__ __forceinline__ void stage_etile(const _Float16* __restrict__ ef,
                                                   char* esp, int c0, int k0,
                                                   int w, int lane) {
  #pragma unroll
  for (int q = 0; q < 2; ++q) {
    const int u = q * 1024 + w * 64 + lane;
    const int chunk = u >> 9, off = u & 511;
    GLOAD_LDS16(ef + ((size_t)(c0 + chunk) * K_CB + k0 + off) * 8,
                (_Float16*)esp + (size_t)(q * 1024 + w * 64) * 8);
  }
}

// ===========================================================================
// Main R9b (resubmit of R9 after infra failure; audit found no hang path;
// cleaned the acc-init self-assignment UB): 2-phase double-buffered
// e-staging (T3-minimum). R8 post-mortem: K-loop time ~170us invariant to
// MFMA/LDS/e-byte shape; per-iteration cost ~= SUM of pipe costs -> the
// per-wave a-load->vmcnt->MFMA chain serializes pipes (compiler sinks
// source prefetch, R1). Fix: e streams via global_load_lds into a
// double-buffered 32KB sub-tile (512 codes x 32 dims); per phase
// {STAGE(next); compute 8 MFMAs from cur; barrier}. Loads for tile t+1 fly
// across compute of t; one drain/phase at the barrier. e-dedup restored
// (1 GB issued); esq staged in LDS (kills k0-top bubble). LDS 160KB:
// zs 64K | es 2x32K | eqs 32K; 1 block/CU. Wave (th=w>>3, cg=w&7): f=2 x
// j=2, acc[2][2]=64 AGPR; arch ~55 -> ~120 <= 128 @ (1024,4). Spill check:
// WRITE_SIZE stays ~33 MB.
// ===========================================================================
__global__ __launch_bounds__(1024, 4) void vq_main_kernel(
    const float* __restrict__ z, const float* __restrict__ e,
    const float* __restrict__ esq_g,
    const short* __restrict__ eht,
    float* __restrict__ out,
    int* __restrict__ cnt, int* __restrict__ list,
    unsigned long long* __restrict__ fixb, float* __restrict__ zc) {
  extern __shared__ char smem[];
  _Float16* zs = (_Float16*)smem;               // [32 c][128 t][8] f16 = 64 KB
  float* eqs   = (float*)(smem + 131072);       // [8192] f32 = 32 KB

  const int tid  = threadIdx.x;
  const int w    = tid >> 6;          // wave 0..15
  const int lane = tid & 63;
  const int half = lane >> 5;
  const int l31  = lane & 31;
  const int th   = w >> 3;            // token half (0/1): 64 tokens
  const int cg   = w & 7;             // code subgroup: 64 codes (f=2)
  const int n0   = blockIdx.x * 128;  // 256 blocks x 128 tokens
  const _Float16* ef = (const _Float16*)eht;

  // ---- stage all esq once (32 KB, 2 insts/wave) ----
  #pragma unroll
  for (int i = 0; i < 2; ++i) {
    int idx = (w * 2 + i) * 256;
    GLOAD_LDS16(esq_g + idx + lane * 4, eqs + idx);
  }
  // ---- prologue: stage (k0=0, sub-tile 0) into es buffer 0 ----
  stage_etile(ef, smem + 65536, 0, 0, w, lane);

  // ---- convert -2*z to fp16 directly into LDS (fused zprep) ----
  {
    const int t  = tid & 127;
    const int cb = (tid >> 7) * 4;    // 8 thread-groups x 4 c's
    #pragma unroll
    for (int cc = 0; cc < 4; ++cc) {
      const int c = cb + cc;
      f16x8 hv;
      #pragma unroll
      for (int i = 0; i < 8; ++i)
        hv[i] = (_Float16)(-2.0f * z[(size_t)(c * 8 + i) * N_TOK + n0 + t]); // coalesced over t
      *(f16x8*)(zs + ((size_t)c * 128 + t) * 8) = hv;
    }
  }
  __syncthreads();   // publishes zs, eqs, and es buffer 0 (vmcnt drain)

  float bestv[2] = {3.4e38f, 3.4e38f};
  float secv[2]  = {3.4e38f, 3.4e38f};
  int   bestk[2] = {0, 0};

  int buf = 0;
  for (int k0 = 0; k0 < K_CB; k0 += 512) {
    const int kb = k0 + cg * 64;

    // ---- acc init = esq broadcast from LDS (f is compile-time: unrolled) ----
    f32x16 acc[2][2];
    #pragma unroll
    for (int f = 0; f < 2; ++f) {
      const int qb = kb + 32 * f + 4 * half;
      #pragma unroll
      for (int g = 0; g < 4; ++g) {
        f32x4 q = *(const f32x4*)(eqs + qb + 8 * g);    // LDS broadcast
        #pragma unroll
        for (int r = 0; r < 4; ++r) {
          acc[f][0][g * 4 + r] = q[r];
          acc[f][1][g * 4 + r] = q[r];
        }
      }
    }

    #pragma unroll 1
    for (int s = 0; s < 8; ++s) {
      // ---- stage next sub-tile into the other buffer (in flight across compute)
      {
        int nc = (s + 1) * 4, nk = k0;
        if (s == 7) { nc = 0; nk = k0 + 512; }
        if (nk < K_CB)
          stage_etile(ef, smem + 65536 + ((buf ^ 1) << 15), nc, nk, w, lane);
      }
      // ---- compute current sub-tile (32 dims = 2 dc steps) ----
      const _Float16* eb = (const _Float16*)(smem + 65536 + (buf << 15));
      #pragma unroll
      for (int dcL = 0; dcL < 2; ++dcL) {
        f16x8 a[2], b[2];
        const int ar = ((2 * dcL + half) << 9) + cg * 64 + l31;   // 16B-unit index
        a[0] = *(const f16x8*)(eb + (size_t)ar * 8);
        a[1] = *(const f16x8*)(eb + (size_t)(ar + 32) * 8);
        const int cglob = s * 4 + 2 * dcL + half;
        const int zb = (cglob * 128 + th * 64 + l31) * 8;
        b[0] = *(const f16x8*)(zs + zb);
        b[1] = *(const f16x8*)(zs + zb + 32 * 8);
        acc[0][0] = __builtin_amdgcn_mfma_f32_32x32x16_f16(a[0], b[0], acc[0][0], 0, 0, 0);
        acc[0][1] = __builtin_amdgcn_mfma_f32_32x32x16_f16(a[0], b[1], acc[0][1], 0, 0, 0);
        acc[1][0] = __builtin_amdgcn_mfma_f32_32x32x16_f16(a[1], b[0], acc[1][0], 0, 0, 0);
        acc[1][1] = __builtin_amdgcn_mfma_f32_32x32x16_f16(a[1], b[1], acc[1][1], 0, 0, 0);
      }
      __syncthreads();   // drains stage (publishes next tile), guards buffer reuse
      buf ^= 1;
    }

    // epilogue: running best/second per token-group j (k ascending per lane)
    #pragma unroll
    for (int f = 0; f < 2; ++f) {
      const int base = kb + 32 * f + 4 * half;
      #pragma unroll
      for (int g = 0; g < 4; ++g) {
        #pragma unroll
        for (int r = 0; r < 4; ++r) {
          const int reg = g * 4 + r;
          const int kglob = base + 8 * g + r;
          #pragma unroll
          for (int j = 0; j < 2; ++j) {
            const float s = acc[f][j][reg];
            if (s < bestv[j]) { secv[j] = bestv[j]; bestv[j] = s; bestk[j] = kglob; }
            else if (s < secv[j]) secv[j] = s;
          }
        }
      }
    }
  }

  // ---- cross-wave merge: 16 partials per token (8 cg x 2 half-lanes) ----
  // reuse zs region (all zs/es reads done at the final phase barrier)
  __syncthreads();
  float* pv  = (float*)(smem);                  // [16][128] = 8 KB
  int*   pk  = (int*)  (smem + 8192);
  float* ps2 = (float*)(smem + 16384);
  int*   fin = (int*)  (smem + 24576);          // [128]
  int*   slo = (int*)  (smem + 25088);          // [128]
  const int slot = cg * 2 + half;
  #pragma unroll
  for (int j = 0; j < 2; ++j) {
    const int t = th * 64 + j * 32 + l31;
    pv [slot * 128 + t] = bestv[j];
    pk [slot * 128 + t] = bestk[j];
    ps2[slot * 128 + t] = secv[j];
  }
  __syncthreads();
  if (tid < 128) {
    const int t = tid;
    float bv = pv[t]; int bk = pk[t]; float sc = ps2[t];
    #pragma unroll
    for (int s2 = 1; s2 < 16; ++s2) {
      float v = pv[s2 * 128 + t]; int k2 = pk[s2 * 128 + t]; float s3 = ps2[s2 * 128 + t];
      if (v < bv || (v == bv && k2 < bk)) { sc = fminf(bv, s3); bv = v; bk = k2; }
      else                                { sc = fminf(sc, v); }
    }
    fin[t] = bk;
    int sl = -1;
    const int n = n0 + t;
    out[(size_t)D_DIM * N_TOK + n] = (float)bk;     // indices as float (exact)
    if (sc - bv < TAU) {                            // flag for exact rescan
      int p = atomicAdd(cnt, 1);
      list[p] = n;
      fixb[n] = 0xFFFFFFFFFFFFFFFFULL;
      if (p < ZC_CAP) sl = p;
    }
    slo[t] = sl;
  }
  __syncthreads();

  // ---- compact flagged z columns into zc (coalesced source for rescan) ----
  for (int tt = 0; tt < 128; ++tt) {
    const int p = slo[tt];                          // uniform broadcast
    if (p >= 0 && tid < 256)
      zc[(size_t)p * 256 + tid] = z[(size_t)tid * N_TOK + n0 + tt];
  }

  // ---- z_q gather: float4 codebook loads, coalesced stores over t ----
  {
    const int t = tid & 127, d0 = tid >> 7;         // d0 0..7
    const int kk = fin[t];
    const f32x4* row = (const f32x4*)(e + (size_t)kk * D_DIM) + d0 * 8;
    #pragma unroll 4
    for (int q = 0; q < 8; ++q) {
      f32x4 v = row[q];
      const int d = d0 * 32 + q * 4;
      out[(size_t)(d + 0) * N_TOK + n0 + t] = v[0];
      out[(size_t)(d + 1) * N_TOK + n0 + t] = v[1];
      out[(size_t)(d + 2) * N_TOK + n0 + t] = v[2];
      out[(size_t)(d + 3) * N_TOK + n0 + t] = v[3];
    }
  }
}

// ===========================================================================
// C2: exact fp32 rescan + finisher. Items = (64-token group) x (256-code
// slab); SLABS=32 items per group. Stage is bank-conflict-free (thread t
// owns token t -> consecutive LDS addresses). zc path coalesced f32x4;
// groups >= ZC_CAP/64 fall back to scattered z reads. atomicMin-merges
// packed (f32bits<<32|k); last-finishing item of a group writes idx + z_q.
// ===========================================================================
__global__ __launch_bounds__(256) void rescan_kernel(
    const float* __restrict__ z, const float* __restrict__ zc,
    const float* __restrict__ e,
    const float* __restrict__ esq, const int* __restrict__ cnt,
    const int* __restrict__ list, unsigned long long* __restrict__ fixb,
    int* __restrict__ gdone, float* __restrict__ out) {
  __shared__ float zs[D_DIM * 64];                 // 64 KB, zs[d*64 + t]
  __shared__ unsigned long long red[16 * 64];      // 8 KB
  __shared__ int fk[64], fn[64], lastflag;
  const int tid = threadIdx.x;
  const int c = *(volatile const int*)cnt;
  if (c == 0) return;
  int groups = (c + 63) >> 6;
  if (groups > MAXGRP) groups = MAXGRP;
  const int items = groups * SLABS;
  const int tx = tid & 15, ty = tid >> 4;

  for (int it = blockIdx.x; it < items; it += gridDim.x) {
    const int g = it / SLABS;
    const int slab = (it % SLABS) * SLABW;
    __syncthreads();                               // protect zs/red reuse
    // ---- stage z columns for this group ----
    if (g < (ZC_CAP >> 6)) {
      // compact path: thread t owns token t -> conflict-free LDS writes
      const int t = tid & 63, seg = tid >> 6;      // seg 0..3 (64 d's each)
      const int idx = g * 64 + t;
      const float* src = zc + (size_t)(idx < c ? idx : c - 1) * 256 + seg * 64;
      #pragma unroll
      for (int r = 0; r < 16; ++r) {
        f32x4 v = *(const f32x4*)(src + r * 4);
        const int d = seg * 64 + r * 4;
        zs[(d + 0) * 64 + t] = v[0];
        zs[(d + 1) * 64 + t] = v[1];
        zs[(d + 2) * 64 + t] = v[2];
        zs[(d + 3) * 64 + t] = v[3];
      }
    } else {
      // overflow fallback: scattered reads from z
      const int t = tid & 63, dq = tid >> 6;       // dq 0..3
      const int idx = g * 64 + t;
      const int n = list[idx < c ? idx : c - 1];
      #pragma unroll 4
      for (int dd = 0; dd < 64; ++dd) {
        const int d = dq * 64 + dd;
        zs[d * 64 + t] = z[(size_t)d * N_TOK + n];
      }
    }
    __syncthreads();

    unsigned long long lmin[4] = {~0ULL, ~0ULL, ~0ULL, ~0ULL};
    #pragma unroll
    for (int k0 = 0; k0 < SLABW; k0 += 64) {
      const f32x4* er[4]; float eqv[4];
      #pragma unroll
      for (int j = 0; j < 4; ++j) {
        int k = slab + k0 + ty + 16 * j;
        er[j] = (const f32x4*)(e + (size_t)k * D_DIM);
        eqv[j] = esq[k];
      }
      float acc[4][4];
      #pragma unroll
      for (int i = 0; i < 4; ++i)
        #pragma unroll
        for (int j = 0; j < 4; ++j) acc[i][j] = 0.f;
      #pragma unroll 4
      for (int d4 = 0; d4 < D_DIM / 4; ++d4) {
        f32x4 ev[4];
        #pragma unroll
        for (int j = 0; j < 4; ++j) ev[j] = er[j][d4];
        #pragma unroll
        for (int dd = 0; dd < 4; ++dd) {
          float zv[4];
          #pragma unroll
          for (int i = 0; i < 4; ++i) zv[i] = zs[(d4 * 4 + dd) * 64 + tx + 16 * i];
          #pragma unroll
          for (int i = 0; i < 4; ++i)
            #pragma unroll
            for (int j = 0; j < 4; ++j) acc[i][j] += zv[i] * ev[j][dd];
        }
      }
      #pragma unroll
      for (int j = 0; j < 4; ++j) {
        const int k = slab + k0 + ty + 16 * j;
        #pragma unroll
        for (int i = 0; i < 4; ++i) {
          float s = eqv[j] - 2.0f * acc[i][j] + 1024.0f;   // bias > 0 for packing
          unsigned long long p =
              ((unsigned long long)__float_as_uint(s) << 32) | (unsigned)k;
          lmin[i] = (p < lmin[i]) ? p : lmin[i];
        }
      }
    }
    #pragma unroll
    for (int i = 0; i < 4; ++i) red[ty * 64 + tx + 16 * i] = lmin[i];
    __syncthreads();
    if (tid < 64) {
      unsigned long long m = red[tid];
      #pragma unroll
      for (int t = 1; t < 16; ++t) {
        unsigned long long v = red[t * 64 + tid];
        m = (v < m) ? v : m;
      }
      const int idx = g * 64 + tid;
      const int n = list[idx < c ? idx : c - 1];
      atomicMin(&fixb[n], m);
    }
    // ---- completion: last item of this group writes outputs ----
    __threadfence();
    __syncthreads();
    if (tid == 0) lastflag = (atomicAdd(&gdone[g], 1) == SLABS - 1) ? 1 : 0;
    __syncthreads();
    if (lastflag) {
      if (tid < 64) {
        const int idx = g * 64 + tid;
        int kres = -1, n = -1;
        if (idx < c) {
          n = list[idx];
          unsigned long long mv = atomicMin(&fixb[n], 0xFFFFFFFFFFFFFFFFULL);
          kres = (int)(unsigned)(mv & 0xFFFFFFFFu);
          out[(size_t)D_DIM * N_TOK + n] = (float)kres;
        }
        fk[tid] = kres; fn[tid] = n;
      }
      __syncthreads();
      {
        const int t = tid & 63, dq = tid >> 6;
        const int kres = fk[t];
        if (kres >= 0) {
          const int n = fn[t];
          const float* row = e + (size_t)kres * D_DIM;
          #pragma unroll 4
          for (int dd = 0; dd < 64; ++dd) {
            const int d = dq * 64 + dd;
            out[(size_t)d * N_TOK + n] = row[d];
          }
        }
      }
    }
  }
}

// ======================= fallback (round-1 fp32 path) =======================
__global__ __launch_bounds__(256) void esq_kernel(const float* __restrict__ e,
                                                  float* __restrict__ esq) {
  const int wave = threadIdx.x >> 6, lane = threadIdx.x & 63;
  const int k = blockIdx.x * 4 + wave;
  const float4* row = (const float4*)(e + (size_t)k * D_DIM);
  float4 v = row[lane];
  float s = v.x*v.x + v.y*v.y + v.z*v.z + v.w*v.w;
  #pragma unroll
  for (int off = 32; off > 0; off >>= 1) s += __shfl_down(s, off, 64);
  if (lane == 0) esq[k] = s;
}

__global__ __launch_bounds__(256) void vq_kernel(const float* __restrict__ z,
                                                 const float* __restrict__ e,
                                                 const float* __restrict__ esq,
                                                 float* __restrict__ out) {
  __shared__ float zs[D_DIM][64];
  const int tid = threadIdx.x, tx = tid & 15, ty = tid >> 4;
  const int n0 = blockIdx.x * 64;
  {
    const int c = tid & 63, d0 = tid >> 6;
    #pragma unroll 4
    for (int d = d0; d < D_DIM; d += 4) zs[d][c] = z[(size_t)d * N_TOK + n0 + c];
  }
  __syncthreads();
  float bestv[4] = {3.4e38f,3.4e38f,3.4e38f,3.4e38f};
  int   besti[4] = {0,0,0,0};
  for (int k0 = 0; k0 < K_CB; k0 += 64) {
    const float4* er[4]; float eqv[4];
    #pragma unroll
    for (int j = 0; j < 4; ++j) {
      int k = k0 + ty + 16 * j;
      er[j] = (const float4*)(e + (size_t)k * D_DIM);
      eqv[j] = esq[k];
    }
    float acc[4][4];
    #pragma unroll
    for (int i = 0; i < 4; ++i)
      #pragma unroll
      for (int j = 0; j < 4; ++j) acc[i][j] = 0.f;
    #pragma unroll 4
    for (int d4 = 0; d4 < D_DIM/4; ++d4) {
      float4 ev[4];
      #pragma unroll
      for (int j = 0; j < 4; ++j) ev[j] = er[j][d4];
      #pragma unroll
      for (int dd = 0; dd < 4; ++dd) {
        float zv[4];
        #pragma unroll
        for (int i = 0; i < 4; ++i) zv[i] = zs[d4*4+dd][tx + 16*i];
        #pragma unroll
        for (int i = 0; i < 4; ++i)
          #pragma unroll
          for (int j = 0; j < 4; ++j) acc[i][j] += zv[i] * ((const float*)&ev[j])[dd];
      }
    }
    #pragma unroll
    for (int j = 0; j < 4; ++j) {
      int k = k0 + ty + 16 * j;
      #pragma unroll
      for (int i = 0; i < 4; ++i) {
        float s = eqv[j] - 2.0f * acc[i][j];
        if (s < bestv[i]) { bestv[i] = s; besti[i] = k; }
      }
    }
  }
  __syncthreads();
  float* lds = &zs[0][0];
  float* vred = lds; int* ired = (int*)lds + 1024; int* fin = (int*)lds + 2048;
  #pragma unroll
  for (int i = 0; i < 4; ++i) {
    int l = tx + 16 * i;
    vred[ty * 64 + l] = bestv[i]; ired[ty * 64 + l] = besti[i];
  }
  __syncthreads();
  if (tid < 64) {
    float bv = vred[tid]; int bi = ired[tid];
    #pragma unroll
    for (int t = 1; t < 16; ++t) {
      float v = vred[t*64+tid]; int ix = ired[t*64+tid];
      if (v < bv || (v == bv && ix < bi)) { bv = v; bi = ix; }
    }
    fin[tid] = bi;
    out[(size_t)D_DIM * N_TOK + n0 + tid] = (float)bi;
  }
  __syncthreads();
  {
    const int l = tid & 63, d0 = tid >> 6;
    const int kk = fin[l];
    const float* row = e + (size_t)kk * D_DIM;
    #pragma unroll 4
    for (int d = d0; d < D_DIM; d += 4) out[(size_t)d * N_TOK + n0 + l] = row[d];
  }
}

extern "C" void kernel_launch(void* const* d_in, const int* in_sizes, int n_in,
                              void* d_out, int out_size, void* d_ws, size_t ws_size,
                              hipStream_t stream) {
  const float* z = (const float*)d_in[0];
  const float* e = (const float*)d_in[1];
  float* out = (float*)d_out;
  char* ws = (char*)d_ws;

  if (ws_size >= WS_NEED) {
    float* esq = (float*)(ws + OFF_ESQ);
    int* cnt = (int*)(ws + OFF_CNT);
    int* gdone = (int*)(ws + OFF_GDONE);
    int* list = (int*)(ws + OFF_LIST);
    unsigned long long* fixb = (unsigned long long*)(ws + OFF_FIXB);
    short* eht = (short*)(ws + OFF_EHT);
    float* zc = (float*)(ws + OFF_ZC);

    (void)hipFuncSetAttribute((const void*)vq_main_kernel,
                              hipFuncAttributeMaxDynamicSharedMemorySize, SMEM_MAIN);

    eprep_kernel<<<128, 256, 0, stream>>>(e, eht, esq, cnt, gdone);
    vq_main_kernel<<<256, 1024, SMEM_MAIN, stream>>>(z, e, esq, eht,
                                                     out, cnt, list, fixb, zc);
    rescan_kernel<<<512, 256, 0, stream>>>(z, zc, e, esq, cnt, list, fixb, gdone, out);
  } else {
    float* esq = (float*)(ws);
    esq_kernel<<<K_CB / 4, 256, 0, stream>>>(e, esq);
    vq_kernel<<<N_TOK / 64, 256, 0, stream>>>(z, e, esq, out);
  }
}